// Round 5
// baseline (330.271 us; speedup 1.0000x reference)
//
#include <hip/hip_runtime.h>

#define D1 8
#define D2 16
#define HH 64
#define WW 64
#define SPATIAL (D1*D2*HH*WW)   // 524288
#define EPS 1e-5f
#define NEG 0.2f

// padded layouts
#define PA 10
#define PB 18
#define PH 66
#define PW 66
// imgTp: [ap][bp][h][w][ci16]  strides (u16): w=16, h=1056, plane=69696, ap=1254528
#define IT_H 1056
#define IT_P 69696
#define IT_A 1254528
// y1p:  [ap][bp][h][w][co32]  strides (u16): w=32, h=2112, plane=139392, ap=2509056
#define Y1_H 2112
#define Y1_P 139392
#define Y1_A 2509056

typedef unsigned short u16;
typedef __attribute__((ext_vector_type(8))) short s16x8;
typedef __attribute__((ext_vector_type(8))) unsigned short u16x8;
typedef __attribute__((ext_vector_type(4))) unsigned short u16x4;
typedef __attribute__((ext_vector_type(4))) float f32x4;

__device__ __forceinline__ u16 f2bf(float f) {
    unsigned int u = __builtin_bit_cast(unsigned int, f);
    return (u16)((u + 0x7FFFu + ((u >> 16) & 1u)) >> 16);   // RNE
}
__device__ __forceinline__ float bf2f(u16 u) {
    unsigned int v = ((unsigned int)u) << 16;
    return __builtin_bit_cast(float, v);
}
__device__ __forceinline__ float leaky(float x) {
    return x >= 0.f ? x : NEG * x;
}

// XCD swizzle: b-PAIR per XCD (db-halo L2 reuse); h-tiles+a consecutive.
__device__ __forceinline__ void decode_block(int flat, int& a, int& b, int& h0) {
    int xcd  = flat & 7;
    int slot = flat >> 3;
    int ht   = slot & 7;
    int b0   = (slot >> 3) & 1;
    a        = (slot >> 4) & 7;
    b        = xcd * 2 + b0;
    h0       = ht * 8;
}

// ---------------------------------------------------------------------------
// Weight transforms
// w1t: [p(9)][dh(3)][grp(2)][co(32)][k(32)]
//      grp0: k = dw(0/1)*16 + ci(16); grp1: k = ci(16) for dw=2, upper 16 = 0
// w2t: [p(9)][tap(9)][co(32)][ci(32)]
// ---------------------------------------------------------------------------
__global__ __launch_bounds__(256) void wtrans1(const float* __restrict__ w,
                                               u16* __restrict__ o) {
    int i = blockIdx.x * 256 + threadIdx.x;
    if (i >= 55296) return;
    int k    = i & 31;
    int co   = (i >> 5) & 31;
    int grp  = (i >> 10) & 1;
    int rest = i >> 11;           // p*3+dh
    int dh   = rest % 3;
    int p    = rest / 3;
    int da = p / 3, db = p % 3;
    float v = 0.f;
    if (grp == 0) {
        int dw = k >> 4, ci = k & 15;
        v = w[((((co * 16 + ci) * 3 + da) * 3 + db) * 3 + dh) * 3 + dw];
    } else if (k < 16) {
        v = w[((((co * 16 + k) * 3 + da) * 3 + db) * 3 + dh) * 3 + 2];
    }
    o[i] = f2bf(v);
}

__global__ __launch_bounds__(256) void wtrans2(const float* __restrict__ w,
                                               u16* __restrict__ o) {
    int i = blockIdx.x * 256 + threadIdx.x;
    if (i >= 82944) return;
    int ci = i & 31;
    int co = (i >> 5) & 31;
    int t  = (i >> 10) % 9;
    int p  = (i >> 10) / 9;
    int da = p / 3, db = p % 3, dh = t / 3, dw = t % 3;
    o[i] = f2bf(w[((((co * 32 + ci) * 3 + da) * 3 + db) * 3 + dh) * 3 + dw]);
}

// ---------------------------------------------------------------------------
// Image: [ci16][spatial] fp32 -> padded channel-last bf16 imgTp
// ---------------------------------------------------------------------------
__global__ __launch_bounds__(256) void imgtrans(const float* __restrict__ img,
                                                u16* __restrict__ o) {
    int p = blockIdx.x * 256 + threadIdx.x;
    int a = p >> 16, b = (p >> 12) & 15, h = (p >> 6) & 63, w = p & 63;
    u16 r[16];
    #pragma unroll
    for (int c = 0; c < 16; ++c)
        r[c] = f2bf(img[(size_t)c * SPATIAL + p]);
    u16x8 lo, hi;
    #pragma unroll
    for (int j = 0; j < 8; ++j) { lo[j] = r[j]; hi[j] = r[8 + j]; }
    size_t off = (size_t)(a + 1) * IT_A + (size_t)(b + 1) * IT_P
               + (h + 1) * IT_H + (w + 1) * 16;
    u16x8* dst = (u16x8*)(o + off);
    dst[0] = lo;
    dst[1] = hi;
}

// ---------------------------------------------------------------------------
// Conv1: barrier-free. A-frags direct from padded global imgTp; 12 resident
// B-frags/plane; dh-sharing (frag(x,grp) feeds 3 dh x 2 nt).
// ---------------------------------------------------------------------------
__global__ __launch_bounds__(256, 3)
void conv1_mfma(const u16* __restrict__ xTp, const u16* __restrict__ w1t,
                u16* __restrict__ y1p, float* __restrict__ st1)
{
    __shared__ float sred[64];
    const int tid = threadIdx.x;
    int a, b, h0;
    decode_block(blockIdx.x, a, b, h0);
    const int lane = tid & 63;
    const int wv   = tid >> 6;
    const int kq   = lane >> 4;
    const int m    = lane & 15;
    const int wseg = wv << 4;

    unsigned pm = 0;
    #pragma unroll
    for (int p = 0; p < 9; ++p) {
        int ap = a + p / 3 - 1, bp = b + p % 3 - 1;
        if (ap >= 0 && ap < D1 && bp >= 0 && bp < D2) pm |= 1u << p;
    }

    f32x4 acc[8][2];
    #pragma unroll
    for (int i = 0; i < 8; ++i)
        #pragma unroll
        for (int nt = 0; nt < 2; ++nt)
            acc[i][nt] = (f32x4)0.f;

    // per-lane A offsets within a row
    const int aoff0 = (wseg + (kq >> 1) + m) * 16 + (kq & 1) * 8;  // grp0
    const int aoff1 = (wseg + 2 + m) * 16 + (kq & 1) * 8;          // grp1

    for (int p = 0; p < 9; ++p) {
        if (!((pm >> p) & 1)) continue;
        const int da = p / 3, db = p % 3;
        const u16* rowp = xTp + (size_t)(a + da) * IT_A + (size_t)(b + db) * IT_P
                        + h0 * IT_H;
        const u16* wb = w1t + p * 6144;

        s16x8 bf[3][2][2];   // [dh][grp][nt]
        #pragma unroll
        for (int dh = 0; dh < 3; ++dh)
            #pragma unroll
            for (int grp = 0; grp < 2; ++grp) {
                const u16* wg = wb + (dh * 2 + grp) * 1024;
                bf[dh][grp][0] = *(const s16x8*)(wg + m * 32 + kq * 8);
                bf[dh][grp][1] = *(const s16x8*)(wg + (m + 16) * 32 + kq * 8);
            }

        #pragma unroll
        for (int x = 0; x < 10; ++x) {
            const u16* rp = rowp + x * IT_H;
            s16x8 a0 = *(const s16x8*)(rp + aoff0);
            s16x8 a1 = *(const s16x8*)(rp + aoff1);
            #pragma unroll
            for (int dh = 0; dh < 3; ++dh) {
                int i = x - dh;
                if (i >= 0 && i < 8) {
                    acc[i][0] = __builtin_amdgcn_mfma_f32_16x16x32_bf16(a0, bf[dh][0][0], acc[i][0], 0, 0, 0);
                    acc[i][1] = __builtin_amdgcn_mfma_f32_16x16x32_bf16(a0, bf[dh][0][1], acc[i][1], 0, 0, 0);
                    acc[i][0] = __builtin_amdgcn_mfma_f32_16x16x32_bf16(a1, bf[dh][1][0], acc[i][0], 0, 0, 0);
                    acc[i][1] = __builtin_amdgcn_mfma_f32_16x16x32_bf16(a1, bf[dh][1][1], acc[i][1], 0, 0, 0);
                }
            }
        }
    }

    // epilogue: channel-last bf16 into y1p interior + fused stats
    if (tid < 64) sred[tid] = 0.f;
    __syncthreads();

    float s[2] = {0.f, 0.f}, s2[2] = {0.f, 0.f};
    const size_t ob = (size_t)(a + 1) * Y1_A + (size_t)(b + 1) * Y1_P;
    #pragma unroll
    for (int i = 0; i < 8; ++i) {
        int h = h0 + i + 1;
        int w0 = wseg + kq * 4 + 1;
        #pragma unroll
        for (int nt = 0; nt < 2; ++nt) {
            int co = m + nt * 16;
            #pragma unroll
            for (int reg = 0; reg < 4; ++reg) {
                float v = acc[i][nt][reg];
                s[nt]  += v;
                s2[nt] += v * v;
                y1p[ob + h * Y1_H + (w0 + reg) * 32 + co] = f2bf(v);
            }
        }
    }
    #pragma unroll
    for (int nt = 0; nt < 2; ++nt) {
        s[nt]  += __shfl_xor(s[nt], 16);  s[nt]  += __shfl_xor(s[nt], 32);
        s2[nt] += __shfl_xor(s2[nt], 16); s2[nt] += __shfl_xor(s2[nt], 32);
    }
    if (kq == 0) {
        atomicAdd(&sred[m * 2],            s[0]);
        atomicAdd(&sred[m * 2 + 1],        s2[0]);
        atomicAdd(&sred[(m + 16) * 2],     s[1]);
        atomicAdd(&sred[(m + 16) * 2 + 1], s2[1]);
    }
    __syncthreads();
    if (tid < 64) atomicAdd(&st1[tid], sred[tid]);
}

// ---------------------------------------------------------------------------
// norm1: in-place instance-norm + leaky on y1p interior rows.
// One block per (a,b,h) row: 64 pos x 32 ch = 4096 B.
// ---------------------------------------------------------------------------
__global__ __launch_bounds__(256)
void norm1_kernel(u16* __restrict__ y1p, const float* __restrict__ st1)
{
    const int tid = threadIdx.x;
    const int r   = blockIdx.x;             // 0..8191
    const int a   = r >> 10;
    const int b   = (r >> 6) & 15;
    const int h   = r & 63;
    const int q   = tid & 3;
    const float invN = 1.f / (float)SPATIAL;
    float mean[8], scl[8];
    #pragma unroll
    for (int j = 0; j < 8; ++j) {
        int ci  = q * 8 + j;
        float mu = st1[ci * 2] * invN;
        float va = st1[ci * 2 + 1] * invN - mu * mu;
        mean[j] = mu;
        scl[j]  = rsqrtf(va + EPS);
    }
    size_t base = (size_t)(a + 1) * Y1_A + (size_t)(b + 1) * Y1_P
                + (h + 1) * Y1_H + 32;      // w_pad = 1
    u16x8* ptr = (u16x8*)(y1p + base) + tid;
    u16x8 v = *ptr;
    u16x8 o;
    #pragma unroll
    for (int j = 0; j < 8; ++j)
        o[j] = f2bf(leaky((bf2f(v[j]) - mean[j]) * scl[j]));
    *ptr = o;
}

// ---------------------------------------------------------------------------
// Conv2: barrier-free. A-frags direct from padded global y1p; 18 resident
// B-frags/plane; per x: 3 A-loads feed 18 MFMAs.
// ---------------------------------------------------------------------------
__global__ __launch_bounds__(256, 3)
void conv2_mfma(const u16* __restrict__ y1p, const u16* __restrict__ w2t,
                u16* __restrict__ y2, float* __restrict__ st2)
{
    __shared__ float sred[64];
    const int tid = threadIdx.x;
    int a, b, h0;
    decode_block(blockIdx.x, a, b, h0);
    const int lane = tid & 63;
    const int wv   = tid >> 6;
    const int kq   = lane >> 4;
    const int m    = lane & 15;
    const int wseg = wv << 4;

    unsigned pm = 0;
    #pragma unroll
    for (int p = 0; p < 9; ++p) {
        int ap = a + p / 3 - 1, bp = b + p % 3 - 1;
        if (ap >= 0 && ap < D1 && bp >= 0 && bp < D2) pm |= 1u << p;
    }

    f32x4 acc[8][2];
    #pragma unroll
    for (int i = 0; i < 8; ++i)
        #pragma unroll
        for (int nt = 0; nt < 2; ++nt)
            acc[i][nt] = (f32x4)0.f;

    const int aoff = (wseg + m) * 32 + kq * 8;   // + dw*32 per dw

    for (int p = 0; p < 9; ++p) {
        if (!((pm >> p) & 1)) continue;
        const int da = p / 3, db = p % 3;
        const u16* rowp = y1p + (size_t)(a + da) * Y1_A + (size_t)(b + db) * Y1_P
                        + h0 * Y1_H;
        const u16* wb = w2t + p * 9216;

        s16x8 bf[3][3][2];   // [dh][dw][nt]
        #pragma unroll
        for (int dh = 0; dh < 3; ++dh)
            #pragma unroll
            for (int dw = 0; dw < 3; ++dw) {
                const u16* wg = wb + (dh * 3 + dw) * 1024;
                bf[dh][dw][0] = *(const s16x8*)(wg + m * 32 + kq * 8);
                bf[dh][dw][1] = *(const s16x8*)(wg + (m + 16) * 32 + kq * 8);
            }

        #pragma unroll
        for (int x = 0; x < 10; ++x) {
            const u16* rp = rowp + x * Y1_H + aoff;
            s16x8 a0 = *(const s16x8*)(rp);
            s16x8 a1 = *(const s16x8*)(rp + 32);
            s16x8 a2 = *(const s16x8*)(rp + 64);
            #pragma unroll
            for (int dh = 0; dh < 3; ++dh) {
                int i = x - dh;
                if (i >= 0 && i < 8) {
                    acc[i][0] = __builtin_amdgcn_mfma_f32_16x16x32_bf16(a0, bf[dh][0][0], acc[i][0], 0, 0, 0);
                    acc[i][1] = __builtin_amdgcn_mfma_f32_16x16x32_bf16(a0, bf[dh][0][1], acc[i][1], 0, 0, 0);
                    acc[i][0] = __builtin_amdgcn_mfma_f32_16x16x32_bf16(a1, bf[dh][1][0], acc[i][0], 0, 0, 0);
                    acc[i][1] = __builtin_amdgcn_mfma_f32_16x16x32_bf16(a1, bf[dh][1][1], acc[i][1], 0, 0, 0);
                    acc[i][0] = __builtin_amdgcn_mfma_f32_16x16x32_bf16(a2, bf[dh][2][0], acc[i][0], 0, 0, 0);
                    acc[i][1] = __builtin_amdgcn_mfma_f32_16x16x32_bf16(a2, bf[dh][2][1], acc[i][1], 0, 0, 0);
                }
            }
        }
    }

    // epilogue: channel-first bf16 y2 + fused stats
    if (tid < 64) sred[tid] = 0.f;
    __syncthreads();

    float s[2] = {0.f, 0.f}, s2[2] = {0.f, 0.f};
    #pragma unroll
    for (int i = 0; i < 8; ++i) {
        int h  = h0 + i;
        int w0 = wseg + kq * 4;
        #pragma unroll
        for (int nt = 0; nt < 2; ++nt) {
            int co = m + nt * 16;
            u16x4 pk;
            #pragma unroll
            for (int reg = 0; reg < 4; ++reg) {
                float v = acc[i][nt][reg];
                s[nt]  += v;
                s2[nt] += v * v;
                pk[reg] = f2bf(v);
            }
            size_t off = ((size_t)(co * D1 + a) * D2 + b) * (HH * WW) + h * WW + w0;
            *(u16x4*)(y2 + off) = pk;
        }
    }
    #pragma unroll
    for (int nt = 0; nt < 2; ++nt) {
        s[nt]  += __shfl_xor(s[nt], 16);  s[nt]  += __shfl_xor(s[nt], 32);
        s2[nt] += __shfl_xor(s2[nt], 16); s2[nt] += __shfl_xor(s2[nt], 32);
    }
    if (kq == 0) {
        atomicAdd(&sred[m * 2],            s[0]);
        atomicAdd(&sred[m * 2 + 1],        s2[0]);
        atomicAdd(&sred[(m + 16) * 2],     s[1]);
        atomicAdd(&sred[(m + 16) * 2 + 1], s2[1]);
    }
    __syncthreads();
    if (tid < 64) atomicAdd(&st2[tid], sred[tid]);
}

// ---------------------------------------------------------------------------
// Final: norm + leaky, bf16 channel-first -> fp32 channel-first d_out
// ---------------------------------------------------------------------------
__global__ __launch_bounds__(256)
void norm2_kernel(const u16* __restrict__ y2, const float* __restrict__ st2,
                  float* __restrict__ out)
{
    size_t i4 = (size_t)blockIdx.x * 256 + threadIdx.x;
    int c = (int)(i4 >> 17);
    const float invN = 1.f / (float)SPATIAL;
    float mu = st2[c * 2] * invN;
    float va = st2[c * 2 + 1] * invN - mu * mu;
    float sc = rsqrtf(va + EPS);
    u16x4 v = *(const u16x4*)(y2 + i4 * 4);
    float4 o;
    o.x = leaky((bf2f(v[0]) - mu) * sc);
    o.y = leaky((bf2f(v[1]) - mu) * sc);
    o.z = leaky((bf2f(v[2]) - mu) * sc);
    o.w = leaky((bf2f(v[3]) - mu) * sc);
    *(float4*)(out + i4 * 4) = o;
}

// ---------------------------------------------------------------------------
extern "C" void kernel_launch(void* const* d_in, const int* in_sizes, int n_in,
                              void* d_out, int out_size, void* d_ws, size_t ws_size,
                              hipStream_t stream)
{
    const float* image = (const float*)d_in[0];
    const float* w1    = (const float*)d_in[1];
    const float* w2    = (const float*)d_in[2];
    float* out = (float*)d_out;

    // d_out (64 MiB): y1p [0, 50,181,120) | w1t @48MiB | w2t after | norm2
    // overwrites everything last.
    u16* y1p = (u16*)d_out;
    u16* w1t = (u16*)((char*)d_out + 50331648);   // 55296 u16 = 110,592 B
    u16* w2t = (u16*)((char*)d_out + 50442240);   // 82944 u16 = 165,888 B

    // ws: imgTp [0, 25,090,560) | y2 @24MiB (32 MiB) | stats @64MiB
    u16*   imgTp = (u16*)d_ws;
    u16*   y2    = (u16*)((char*)d_ws + 25165824);
    float* st    = (float*)((char*)d_ws + 67108864);
    float* st1   = st;
    float* st2   = st + 64;

    hipMemsetAsync(y1p,   0, 50181120, stream);   // zero halos (+interior)
    hipMemsetAsync(imgTp, 0, 25090560, stream);
    hipMemsetAsync(st,    0, 512,      stream);

    wtrans1<<<216, 256, 0, stream>>>(w1, w1t);
    wtrans2<<<324, 256, 0, stream>>>(w2, w2t);
    imgtrans<<<2048, 256, 0, stream>>>(image, imgTp);

    conv1_mfma<<<1024, 256, 0, stream>>>(imgTp, w1t, y1p, st1);
    norm1_kernel<<<8192, 256, 0, stream>>>(y1p, st1);
    conv2_mfma<<<1024, 256, 0, stream>>>(y1p, w2t, y2, st2);
    norm2_kernel<<<16384, 256, 0, stream>>>(y2, st2, out);
}

// Round 6
// 291.623 us; speedup vs baseline: 1.1325x; 1.1325x over previous
//
#include <hip/hip_runtime.h>

#define D1 8
#define D2 16
#define HH 64
#define WW 64
#define SPATIAL (D1*D2*HH*WW)   // 524288
#define EPS 1e-5f
#define NEG 0.2f

// padded-h/w, compact-a/b layouts (planes outside a/b handled by pm mask)
// imgTp: [a8][b16][h66][w66][ci16]  (u16 strides)
#define IT_H 1056
#define IT_P 69696
#define IT_A 1115136
// y1p:  [a8][b16][h66][w66][co32]
#define Y1_H 2112
#define Y1_P 139392
#define Y1_A 2230272

typedef unsigned short u16;
typedef __attribute__((ext_vector_type(8))) short s16x8;
typedef __attribute__((ext_vector_type(8))) unsigned short u16x8;
typedef __attribute__((ext_vector_type(4))) unsigned short u16x4;
typedef __attribute__((ext_vector_type(4))) float f32x4;

__device__ __forceinline__ u16 f2bf(float f) {
    unsigned int u = __builtin_bit_cast(unsigned int, f);
    return (u16)((u + 0x7FFFu + ((u >> 16) & 1u)) >> 16);   // RNE
}
__device__ __forceinline__ float bf2f(u16 u) {
    unsigned int v = ((unsigned int)u) << 16;
    return __builtin_bit_cast(float, v);
}
__device__ __forceinline__ float leaky(float x) {
    return x >= 0.f ? x : NEG * x;
}

// XCD swizzle: b-PAIR per XCD (db-halo L2 reuse); h-tiles+a consecutive.
__device__ __forceinline__ void decode_block(int flat, int& a, int& b, int& h0) {
    int xcd  = flat & 7;
    int slot = flat >> 3;
    int ht   = slot & 7;
    int b0   = (slot >> 3) & 1;
    a        = (slot >> 4) & 7;
    b        = xcd * 2 + b0;
    h0       = ht * 8;
}

// ---------------------------------------------------------------------------
// Weight transforms
// w1t: [p(9)][dh(3)][grp(2)][co(32)][k(32)]
// w2t: [p(9)][tap(9)][co(32)][ci(32)]
// ---------------------------------------------------------------------------
__global__ __launch_bounds__(256) void wtrans1(const float* __restrict__ w,
                                               u16* __restrict__ o) {
    int i = blockIdx.x * 256 + threadIdx.x;
    if (i >= 55296) return;
    int k    = i & 31;
    int co   = (i >> 5) & 31;
    int grp  = (i >> 10) & 1;
    int rest = i >> 11;           // p*3+dh
    int dh   = rest % 3;
    int p    = rest / 3;
    int da = p / 3, db = p % 3;
    float v = 0.f;
    if (grp == 0) {
        int dw = k >> 4, ci = k & 15;
        v = w[((((co * 16 + ci) * 3 + da) * 3 + db) * 3 + dh) * 3 + dw];
    } else if (k < 16) {
        v = w[((((co * 16 + k) * 3 + da) * 3 + db) * 3 + dh) * 3 + 2];
    }
    o[i] = f2bf(v);
}

__global__ __launch_bounds__(256) void wtrans2(const float* __restrict__ w,
                                               u16* __restrict__ o) {
    int i = blockIdx.x * 256 + threadIdx.x;
    if (i >= 82944) return;
    int ci = i & 31;
    int co = (i >> 5) & 31;
    int t  = (i >> 10) % 9;
    int p  = (i >> 10) / 9;
    int da = p / 3, db = p % 3, dh = t / 3, dw = t % 3;
    o[i] = f2bf(w[((((co * 32 + ci) * 3 + da) * 3 + db) * 3 + dh) * 3 + dw]);
}

// ---------------------------------------------------------------------------
// Zero the h/w halos of imgTp (blocks 0..127) and y1p (blocks 128..255).
// ---------------------------------------------------------------------------
__global__ __launch_bounds__(256) void halo_zero(u16* __restrict__ imgTp,
                                                 u16* __restrict__ y1p) {
    int plane = blockIdx.x;
    bool isY  = plane >= 128;
    int ab = plane & 127;
    int a = ab >> 4, b = ab & 15;
    u16x8 z = (u16x8)0;
    for (int i = threadIdx.x; i < 260; i += 256) {
        int h, w;
        if (i < 66)       { h = 0;        w = i;        }
        else if (i < 132) { h = 65;       w = i - 66;   }
        else if (i < 196) { h = i - 131;  w = 0;        }
        else              { h = i - 195;  w = 65;       }
        if (isY) {
            u16x8* p = (u16x8*)(y1p + (size_t)a * Y1_A + (size_t)b * Y1_P
                                + h * Y1_H + w * 32);
            p[0] = z; p[1] = z; p[2] = z; p[3] = z;
        } else {
            u16x8* p = (u16x8*)(imgTp + (size_t)a * IT_A + (size_t)b * IT_P
                                + h * IT_H + w * 16);
            p[0] = z; p[1] = z;
        }
    }
}

// ---------------------------------------------------------------------------
// Image: [ci16][spatial] fp32 -> padded-h/w channel-last bf16 imgTp
// ---------------------------------------------------------------------------
__global__ __launch_bounds__(256) void imgtrans(const float* __restrict__ img,
                                                u16* __restrict__ o) {
    int p = blockIdx.x * 256 + threadIdx.x;
    int a = p >> 16, b = (p >> 12) & 15, h = (p >> 6) & 63, w = p & 63;
    u16 r[16];
    #pragma unroll
    for (int c = 0; c < 16; ++c)
        r[c] = f2bf(img[(size_t)c * SPATIAL + p]);
    u16x8 lo, hi;
    #pragma unroll
    for (int j = 0; j < 8; ++j) { lo[j] = r[j]; hi[j] = r[8 + j]; }
    size_t off = (size_t)a * IT_A + (size_t)b * IT_P
               + (h + 1) * IT_H + (w + 1) * 16;
    u16x8* dst = (u16x8*)(o + off);
    dst[0] = lo;
    dst[1] = hi;
}

// ---------------------------------------------------------------------------
// Conv1: wave-private LDS staging, NO barriers in the K-loop.
// Wave tile: 10 rows x 18 cols x 16 ch = 360 granules of 8 u16.
// LDS layout per wave: [row10][g2][col18] cells of 8 u16 (stride 288/row).
// ---------------------------------------------------------------------------
__global__ __launch_bounds__(256, 4)
void conv1_mfma(const u16* __restrict__ xTp, const u16* __restrict__ w1t,
                u16* __restrict__ y1p, float* __restrict__ st1)
{
    __shared__ __align__(16) u16 lds[4 * 2880];   // 23040 B
    __shared__ float sred[64];

    const int tid = threadIdx.x;
    int a, b, h0;
    decode_block(blockIdx.x, a, b, h0);
    const int lane = tid & 63;
    const int wv   = tid >> 6;
    const int kq   = lane >> 4;
    const int m    = lane & 15;
    const int wseg = wv << 4;
    u16* wlds = lds + wv * 2880;

    unsigned pm = 0;
    #pragma unroll
    for (int p = 0; p < 9; ++p) {
        int ap = a + p / 3 - 1, bp = b + p % 3 - 1;
        if (ap >= 0 && ap < D1 && bp >= 0 && bp < D2) pm |= 1u << p;
    }

    // staging offsets: granule gi = lane + 64k; [row][col][g] dense order
    int pack[6];   // goff (18b) | loff<<18
    #pragma unroll
    for (int k = 0; k < 6; ++k) {
        int gi  = lane + (k << 6);
        int row = gi / 36, rem = gi - row * 36;
        int col = rem >> 1, g = rem & 1;
        int goff = (h0 + row) * IT_H + (wseg + col) * 16 + g * 8;
        int loff = row * 288 + g * 144 + col * 8;
        pack[k] = goff | (loff << 18);
    }

    f32x4 acc[8][2];
    #pragma unroll
    for (int i = 0; i < 8; ++i)
        #pragma unroll
        for (int nt = 0; nt < 2; ++nt)
            acc[i][nt] = (f32x4)0.f;

    const int fbase = (kq & 1) * 144 + (m + (kq >> 1)) * 8;   // grp0
    const int fbase1 = (kq & 1) * 144 + (m + 2) * 8;          // grp1

    for (int p = 0; p < 9; ++p) {
        if (!((pm >> p) & 1)) continue;
        const int da = p / 3, db = p % 3;
        const u16* src = xTp + (size_t)(a + da - 1) * IT_A
                       + (size_t)(b + db - 1) * IT_P;

        #pragma unroll
        for (int k = 0; k < 6; ++k) {
            if (k == 5 && lane >= 40) break;   // 360 = 5*64 + 40
            int pk = pack[k];
            u16x8 v = *(const u16x8*)(src + (pk & 0x3FFFF));
            *(u16x8*)&wlds[pk >> 18] = v;
        }

        const u16* wb = w1t + p * 6144;
        s16x8 bf[3][2][2];   // [dh][grp][nt]
        #pragma unroll
        for (int dh = 0; dh < 3; ++dh)
            #pragma unroll
            for (int grp = 0; grp < 2; ++grp) {
                const u16* wg = wb + (dh * 2 + grp) * 1024;
                bf[dh][grp][0] = *(const s16x8*)(wg + m * 32 + kq * 8);
                bf[dh][grp][1] = *(const s16x8*)(wg + (m + 16) * 32 + kq * 8);
            }

        #pragma unroll
        for (int x = 0; x < 10; ++x) {
            s16x8 a0 = *(const s16x8*)&wlds[x * 288 + fbase];
            s16x8 a1 = *(const s16x8*)&wlds[x * 288 + fbase1];
            #pragma unroll
            for (int dh = 0; dh < 3; ++dh) {
                int i = x - dh;
                if (i >= 0 && i < 8) {
                    acc[i][0] = __builtin_amdgcn_mfma_f32_16x16x32_bf16(a0, bf[dh][0][0], acc[i][0], 0, 0, 0);
                    acc[i][1] = __builtin_amdgcn_mfma_f32_16x16x32_bf16(a0, bf[dh][0][1], acc[i][1], 0, 0, 0);
                    acc[i][0] = __builtin_amdgcn_mfma_f32_16x16x32_bf16(a1, bf[dh][1][0], acc[i][0], 0, 0, 0);
                    acc[i][1] = __builtin_amdgcn_mfma_f32_16x16x32_bf16(a1, bf[dh][1][1], acc[i][1], 0, 0, 0);
                }
            }
        }
    }

    // epilogue: channel-last bf16 into y1p interior + fused stats
    if (tid < 64) sred[tid] = 0.f;
    __syncthreads();

    float s[2] = {0.f, 0.f}, s2[2] = {0.f, 0.f};
    const size_t ob = (size_t)a * Y1_A + (size_t)b * Y1_P;
    #pragma unroll
    for (int i = 0; i < 8; ++i) {
        int h = h0 + i + 1;
        int w0 = wseg + kq * 4 + 1;
        #pragma unroll
        for (int nt = 0; nt < 2; ++nt) {
            int co = m + nt * 16;
            #pragma unroll
            for (int reg = 0; reg < 4; ++reg) {
                float v = acc[i][nt][reg];
                s[nt]  += v;
                s2[nt] += v * v;
                y1p[ob + h * Y1_H + (w0 + reg) * 32 + co] = f2bf(v);
            }
        }
    }
    #pragma unroll
    for (int nt = 0; nt < 2; ++nt) {
        s[nt]  += __shfl_xor(s[nt], 16);  s[nt]  += __shfl_xor(s[nt], 32);
        s2[nt] += __shfl_xor(s2[nt], 16); s2[nt] += __shfl_xor(s2[nt], 32);
    }
    if (kq == 0) {
        atomicAdd(&sred[m * 2],            s[0]);
        atomicAdd(&sred[m * 2 + 1],        s2[0]);
        atomicAdd(&sred[(m + 16) * 2],     s[1]);
        atomicAdd(&sred[(m + 16) * 2 + 1], s2[1]);
    }
    __syncthreads();
    if (tid < 64) atomicAdd(&st1[tid], sred[tid]);
}

// ---------------------------------------------------------------------------
// norm1: in-place instance-norm + leaky on y1p interior rows.
// ---------------------------------------------------------------------------
__global__ __launch_bounds__(256)
void norm1_kernel(u16* __restrict__ y1p, const float* __restrict__ st1)
{
    const int tid = threadIdx.x;
    const int r   = blockIdx.x;             // 0..8191
    const int a   = r >> 10;
    const int b   = (r >> 6) & 15;
    const int h   = r & 63;
    const int q   = tid & 3;
    const float invN = 1.f / (float)SPATIAL;
    float mean[8], scl[8];
    #pragma unroll
    for (int j = 0; j < 8; ++j) {
        int ci  = q * 8 + j;
        float mu = st1[ci * 2] * invN;
        float va = st1[ci * 2 + 1] * invN - mu * mu;
        mean[j] = mu;
        scl[j]  = rsqrtf(va + EPS);
    }
    size_t base = (size_t)a * Y1_A + (size_t)b * Y1_P
                + (h + 1) * Y1_H + 32;      // w_pad = 1
    u16x8* ptr = (u16x8*)(y1p + base) + tid;
    u16x8 v = *ptr;
    u16x8 o;
    #pragma unroll
    for (int j = 0; j < 8; ++j)
        o[j] = f2bf(leaky((bf2f(v[j]) - mean[j]) * scl[j]));
    *ptr = o;
}

// ---------------------------------------------------------------------------
// Conv2: wave-private LDS staging, NO barriers in the K-loop.
// Wave tile: 10 rows x 18 cols x 32 ch = 720 granules of 8 u16.
// LDS layout per wave: [row10][q4][col18] cells of 8 u16 (stride 576/row).
// ---------------------------------------------------------------------------
__global__ __launch_bounds__(256, 3)
void conv2_mfma(const u16* __restrict__ y1p, const u16* __restrict__ w2t,
                u16* __restrict__ y2, float* __restrict__ st2)
{
    __shared__ __align__(16) u16 lds[4 * 5760];   // 46080 B
    __shared__ float sred[64];

    const int tid = threadIdx.x;
    int a, b, h0;
    decode_block(blockIdx.x, a, b, h0);
    const int lane = tid & 63;
    const int wv   = tid >> 6;
    const int kq   = lane >> 4;
    const int m    = lane & 15;
    const int wseg = wv << 4;
    u16* wlds = lds + wv * 5760;

    unsigned pm = 0;
    #pragma unroll
    for (int p = 0; p < 9; ++p) {
        int ap = a + p / 3 - 1, bp = b + p % 3 - 1;
        if (ap >= 0 && ap < D1 && bp >= 0 && bp < D2) pm |= 1u << p;
    }

    // staging offsets: granule gi = lane + 64k; [row][col][q] dense order
    int pack[12];   // goff (18b) | loff<<18
    #pragma unroll
    for (int k = 0; k < 12; ++k) {
        int gi  = lane + (k << 6);
        int row = gi / 72, rem = gi - row * 72;
        int col = rem >> 2, q = rem & 3;
        int goff = (h0 + row) * Y1_H + (wseg + col) * 32 + q * 8;
        int loff = row * 576 + q * 144 + col * 8;
        pack[k] = goff | (loff << 18);
    }

    f32x4 acc[8][2];
    #pragma unroll
    for (int i = 0; i < 8; ++i)
        #pragma unroll
        for (int nt = 0; nt < 2; ++nt)
            acc[i][nt] = (f32x4)0.f;

    const int fbase = kq * 144 + m * 8;   // + dw*8 per dw

    for (int p = 0; p < 9; ++p) {
        if (!((pm >> p) & 1)) continue;
        const int da = p / 3, db = p % 3;
        const u16* src = y1p + (size_t)(a + da - 1) * Y1_A
                       + (size_t)(b + db - 1) * Y1_P;

        #pragma unroll
        for (int k = 0; k < 12; ++k) {
            if (k == 11 && lane >= 16) break;   // 720 = 11*64 + 16
            int pk = pack[k];
            u16x8 v = *(const u16x8*)(src + (pk & 0x3FFFF));
            *(u16x8*)&wlds[pk >> 18] = v;
        }

        const u16* wb = w2t + p * 9216;
        s16x8 bf[3][3][2];   // [dh][dw][nt]
        #pragma unroll
        for (int dh = 0; dh < 3; ++dh)
            #pragma unroll
            for (int dw = 0; dw < 3; ++dw) {
                const u16* wg = wb + (dh * 3 + dw) * 1024;
                bf[dh][dw][0] = *(const s16x8*)(wg + m * 32 + kq * 8);
                bf[dh][dw][1] = *(const s16x8*)(wg + (m + 16) * 32 + kq * 8);
            }

        #pragma unroll
        for (int x = 0; x < 10; ++x) {
            s16x8 a0 = *(const s16x8*)&wlds[x * 576 + fbase];
            s16x8 a1 = *(const s16x8*)&wlds[x * 576 + fbase + 8];
            s16x8 a2 = *(const s16x8*)&wlds[x * 576 + fbase + 16];
            #pragma unroll
            for (int dh = 0; dh < 3; ++dh) {
                int i = x - dh;
                if (i >= 0 && i < 8) {
                    acc[i][0] = __builtin_amdgcn_mfma_f32_16x16x32_bf16(a0, bf[dh][0][0], acc[i][0], 0, 0, 0);
                    acc[i][1] = __builtin_amdgcn_mfma_f32_16x16x32_bf16(a0, bf[dh][0][1], acc[i][1], 0, 0, 0);
                    acc[i][0] = __builtin_amdgcn_mfma_f32_16x16x32_bf16(a1, bf[dh][1][0], acc[i][0], 0, 0, 0);
                    acc[i][1] = __builtin_amdgcn_mfma_f32_16x16x32_bf16(a1, bf[dh][1][1], acc[i][1], 0, 0, 0);
                    acc[i][0] = __builtin_amdgcn_mfma_f32_16x16x32_bf16(a2, bf[dh][2][0], acc[i][0], 0, 0, 0);
                    acc[i][1] = __builtin_amdgcn_mfma_f32_16x16x32_bf16(a2, bf[dh][2][1], acc[i][1], 0, 0, 0);
                }
            }
        }
    }

    // epilogue: channel-first bf16 y2 + fused stats
    if (tid < 64) sred[tid] = 0.f;
    __syncthreads();

    float s[2] = {0.f, 0.f}, s2[2] = {0.f, 0.f};
    #pragma unroll
    for (int i = 0; i < 8; ++i) {
        int h  = h0 + i;
        int w0 = wseg + kq * 4;
        #pragma unroll
        for (int nt = 0; nt < 2; ++nt) {
            int co = m + nt * 16;
            u16x4 pk;
            #pragma unroll
            for (int reg = 0; reg < 4; ++reg) {
                float v = acc[i][nt][reg];
                s[nt]  += v;
                s2[nt] += v * v;
                pk[reg] = f2bf(v);
            }
            size_t off = ((size_t)(co * D1 + a) * D2 + b) * (HH * WW) + h * WW + w0;
            *(u16x4*)(y2 + off) = pk;
        }
    }
    #pragma unroll
    for (int nt = 0; nt < 2; ++nt) {
        s[nt]  += __shfl_xor(s[nt], 16);  s[nt]  += __shfl_xor(s[nt], 32);
        s2[nt] += __shfl_xor(s2[nt], 16); s2[nt] += __shfl_xor(s2[nt], 32);
    }
    if (kq == 0) {
        atomicAdd(&sred[m * 2],            s[0]);
        atomicAdd(&sred[m * 2 + 1],        s2[0]);
        atomicAdd(&sred[(m + 16) * 2],     s[1]);
        atomicAdd(&sred[(m + 16) * 2 + 1], s2[1]);
    }
    __syncthreads();
    if (tid < 64) atomicAdd(&st2[tid], sred[tid]);
}

// ---------------------------------------------------------------------------
// Final: norm + leaky, bf16 channel-first -> fp32 channel-first d_out
// ---------------------------------------------------------------------------
__global__ __launch_bounds__(256)
void norm2_kernel(const u16* __restrict__ y2, const float* __restrict__ st2,
                  float* __restrict__ out)
{
    size_t i4 = (size_t)blockIdx.x * 256 + threadIdx.x;
    int c = (int)(i4 >> 17);
    const float invN = 1.f / (float)SPATIAL;
    float mu = st2[c * 2] * invN;
    float va = st2[c * 2 + 1] * invN - mu * mu;
    float sc = rsqrtf(va + EPS);
    u16x4 v = *(const u16x4*)(y2 + i4 * 4);
    float4 o;
    o.x = leaky((bf2f(v[0]) - mu) * sc);
    o.y = leaky((bf2f(v[1]) - mu) * sc);
    o.z = leaky((bf2f(v[2]) - mu) * sc);
    o.w = leaky((bf2f(v[3]) - mu) * sc);
    *(float4*)(out + i4 * 4) = o;
}

// ---------------------------------------------------------------------------
extern "C" void kernel_launch(void* const* d_in, const int* in_sizes, int n_in,
                              void* d_out, int out_size, void* d_ws, size_t ws_size,
                              hipStream_t stream)
{
    const float* image = (const float*)d_in[0];
    const float* w1    = (const float*)d_in[1];
    const float* w2    = (const float*)d_in[2];
    float* out = (float*)d_out;

    // d_out (64 MiB): y1p [0, 35,684,352) | w1t @60MiB | w2t after;
    // all dead before norm2 overwrites d_out.
    u16* y1p = (u16*)d_out;
    u16* w1t = (u16*)((char*)d_out + 62914560);   // 110,592 B
    u16* w2t = (u16*)((char*)d_out + 63129600);   // 165,888 B

    // ws: imgTp [0, 17,842,176) | y2 @20MiB (32 MiB) | stats @64MiB
    u16*   imgTp = (u16*)d_ws;
    u16*   y2    = (u16*)((char*)d_ws + 20971520);
    float* st    = (float*)((char*)d_ws + 67108864);
    float* st1   = st;
    float* st2   = st + 64;

    hipMemsetAsync(st, 0, 512, stream);
    halo_zero<<<256, 256, 0, stream>>>(imgTp, y1p);
    wtrans1<<<216, 256, 0, stream>>>(w1, w1t);
    wtrans2<<<324, 256, 0, stream>>>(w2, w2t);
    imgtrans<<<2048, 256, 0, stream>>>(image, imgTp);

    conv1_mfma<<<1024, 256, 0, stream>>>(imgTp, w1t, y1p, st1);
    norm1_kernel<<<8192, 256, 0, stream>>>(y1p, st1);
    conv2_mfma<<<1024, 256, 0, stream>>>(y1p, w2t, y2, st2);
    norm2_kernel<<<16384, 256, 0, stream>>>(y2, st2, out);
}

// Round 7
// 265.903 us; speedup vs baseline: 1.2421x; 1.0967x over previous
//
#include <hip/hip_runtime.h>

#define D1 8
#define D2 16
#define HH 64
#define WW 64
#define SPATIAL (D1*D2*HH*WW)   // 524288
#define EPS 1e-5f
#define NEG 0.2f

typedef unsigned short u16;
typedef __attribute__((ext_vector_type(8))) short s16x8;
typedef __attribute__((ext_vector_type(8))) unsigned short u16x8;
typedef __attribute__((ext_vector_type(4))) unsigned short u16x4;
typedef __attribute__((ext_vector_type(4))) float f32x4;

__device__ __forceinline__ u16 f2bf(float f) {
    unsigned int u = __builtin_bit_cast(unsigned int, f);
    return (u16)((u + 0x7FFFu + ((u >> 16) & 1u)) >> 16);   // RNE
}
__device__ __forceinline__ float bf2f(u16 u) {
    unsigned int v = ((unsigned int)u) << 16;
    return __builtin_bit_cast(float, v);
}
__device__ __forceinline__ float leaky(float x) {
    return x >= 0.f ? x : NEG * x;
}

// XCD swizzle: b-PAIR per XCD (db-halo L2 reuse); h-tiles+a consecutive.
__device__ __forceinline__ void decode_block(int flat, int& a, int& b, int& h0) {
    int xcd  = flat & 7;
    int slot = flat >> 3;
    int ht   = slot & 7;
    int b0   = (slot >> 3) & 1;
    a        = (slot >> 4) & 7;
    b        = xcd * 2 + b0;
    h0       = ht * 8;
}

// ---------------------------------------------------------------------------
// prep: fused imgtrans (blocks 0..2047) + wtrans1 (2048..2263) +
//       wtrans2 (2264..2587) + stats-zero (2588).
// w1t: [p(9)][dh(3)][grp(2)][co(32)][k(32)]
// w2t: [p(9)][tap(9)][co(32)][ci(32)]
// imgT: [spatial][ci16] channel-last bf16
// ---------------------------------------------------------------------------
__global__ __launch_bounds__(256)
void prep(const float* __restrict__ img, const float* __restrict__ w1,
          const float* __restrict__ w2, u16* __restrict__ imgT,
          u16* __restrict__ w1t, u16* __restrict__ w2t, float* __restrict__ st)
{
    const int bid = blockIdx.x;
    const int tid = threadIdx.x;
    if (bid < 2048) {                          // image transpose
        int p = bid * 256 + tid;
        u16 r[16];
        #pragma unroll
        for (int c = 0; c < 16; ++c)
            r[c] = f2bf(img[(size_t)c * SPATIAL + p]);
        u16x8 lo, hi;
        #pragma unroll
        for (int j = 0; j < 8; ++j) { lo[j] = r[j]; hi[j] = r[8 + j]; }
        u16x8* dst = (u16x8*)(imgT + (size_t)p * 16);
        dst[0] = lo;
        dst[1] = hi;
    } else if (bid < 2264) {                   // w1 transform
        int i = (bid - 2048) * 256 + tid;
        if (i >= 55296) return;
        int k    = i & 31;
        int co   = (i >> 5) & 31;
        int grp  = (i >> 10) & 1;
        int rest = i >> 11;           // p*3+dh
        int dh   = rest % 3;
        int p    = rest / 3;
        int da = p / 3, db = p % 3;
        float v = 0.f;
        if (grp == 0) {
            int dw = k >> 4, ci = k & 15;
            v = w1[((((co * 16 + ci) * 3 + da) * 3 + db) * 3 + dh) * 3 + dw];
        } else if (k < 16) {
            v = w1[((((co * 16 + k) * 3 + da) * 3 + db) * 3 + dh) * 3 + 2];
        }
        w1t[i] = f2bf(v);
    } else if (bid < 2588) {                   // w2 transform
        int i = (bid - 2264) * 256 + tid;
        if (i >= 82944) return;
        int ci = i & 31;
        int co = (i >> 5) & 31;
        int t  = (i >> 10) % 9;
        int p  = (i >> 10) / 9;
        int da = p / 3, db = p % 3, dh = t / 3, dw = t % 3;
        w2t[i] = f2bf(w2[((((co * 32 + ci) * 3 + da) * 3 + db) * 3 + dh) * 3 + dw]);
    } else {                                   // stats zero
        if (tid < 128) st[tid] = 0.f;
    }
}

// ---------------------------------------------------------------------------
// Conv1: Cin=16, K = dw(2)x ci(16) packing + dw2 group. Row-shared A-frags.
// LDS pos stride 24 u16 (48B, 16B-aligned): 2-way banks -> free.
// B-frags load FIRST each round; prefetch spread across grp iterations.
// ---------------------------------------------------------------------------
__global__ __launch_bounds__(256, 3)
void conv1_mfma(const u16* __restrict__ xT, const u16* __restrict__ w1t,
                u16* __restrict__ y1, float* __restrict__ st1)
{
    __shared__ __align__(16) u16 lds[660 * 24];   // 31680 B
    __shared__ float sred[64];

    const int tid = threadIdx.x;
    int a, b, h0;
    decode_block(blockIdx.x, a, b, h0);
    const int lane = tid & 63;
    const int wv   = tid >> 6;
    const int kq   = lane >> 4;
    const int m    = lane & 15;
    const int wseg = wv << 4;

    unsigned pm = 0;
    #pragma unroll
    for (int p = 0; p < 9; ++p) {
        int ap = a + p / 3 - 1, bp = b + p % 3 - 1;
        if (ap >= 0 && ap < D1 && bp >= 0 && bp < D2) pm |= 1u << p;
    }

    // plane-invariant staging offsets (6 granules/thread max, 16 B each)
    const int p0 = tid >> 1, g = tid & 1;
    unsigned vmask = 0;
    int goff[6];
    #pragma unroll
    for (int k = 0; k < 6; ++k) {
        int pos = p0 + 128 * k;
        int row = pos / 66, col = pos - row * 66;
        int h = h0 - 1 + row, w = col - 1;
        bool v = (pos < 660) && col >= 1 && col <= 64 && h >= 0 && h < HH;
        goff[k] = v ? (h * WW + w) * 16 + g * 8 : 0;
        vmask |= (unsigned)v << k;
    }
    const int lbase = p0 * 24 + g * 8;

    // zero pad/OOB cells once
    for (int e = tid; e < 660; e += 256) {
        int row = e / 66, col = e - row * 66;
        int h = h0 - 1 + row;
        if (col == 0 || col == 65 || h < 0 || h >= HH) {
            u16x8 z = (u16x8)0;
            *(u16x8*)&lds[e * 24]     = z;
            *(u16x8*)&lds[e * 24 + 8] = z;
        }
    }

    f32x4 acc[8][2];
    #pragma unroll
    for (int i = 0; i < 8; ++i)
        #pragma unroll
        for (int nt = 0; nt < 2; ++nt)
            acc[i][nt] = (f32x4)0.f;

    int p = 0;
    while (!((pm >> p) & 1)) ++p;

    u16x8 pf[6];
    {
        int ap = a + p / 3 - 1, bp = b + p % 3 - 1;
        const u16* src = xT + (size_t)(ap * D2 + bp) * (HH * WW * 16);
        #pragma unroll
        for (int k = 0; k < 6; ++k)
            if ((vmask >> k) & 1) pf[k] = *(const u16x8*)(src + goff[k]);
    }

    while (p < 9) {
        int pn = p + 1;
        while (pn < 9 && !((pm >> pn) & 1)) ++pn;

        #pragma unroll
        for (int k = 0; k < 6; ++k)
            if ((vmask >> k) & 1) *(u16x8*)&lds[lbase + k * 3072] = pf[k];
        __syncthreads();

        const u16* srcn = nullptr;
        if (pn < 9)
            srcn = xT + (size_t)((a + pn / 3 - 1) * D2 + (b + pn % 3 - 1))
                      * (HH * WW * 16);

        const u16* wbase = w1t + p * 6144;
        #pragma unroll
        for (int grp = 0; grp < 2; ++grp) {
            // B-frags first: first vmem after barrier -> MFMA waits only these
            s16x8 bf[3][2];
            #pragma unroll
            for (int dh = 0; dh < 3; ++dh) {
                const u16* wb = wbase + (dh * 2 + grp) * 1024;
                bf[dh][0] = *(const s16x8*)(wb + m * 32 + kq * 8);
                bf[dh][1] = *(const s16x8*)(wb + (m + 16) * 32 + kq * 8);
            }
            const int cshift = (grp == 0) ? (kq >> 1) : 2;
            const int ebase  = (kq & 1) * 8;
            #pragma unroll
            for (int x = 0; x < 10; ++x) {
                int pos = x * 66 + wseg + m + cshift;
                s16x8 af = *(const s16x8*)&lds[pos * 24 + ebase];
                #pragma unroll
                for (int dh = 0; dh < 3; ++dh) {
                    int i = x - dh;
                    if (i >= 0 && i < 8) {
                        acc[i][0] = __builtin_amdgcn_mfma_f32_16x16x32_bf16(af, bf[dh][0], acc[i][0], 0, 0, 0);
                        acc[i][1] = __builtin_amdgcn_mfma_f32_16x16x32_bf16(af, bf[dh][1], acc[i][1], 0, 0, 0);
                    }
                }
            }
            // progressive prefetch of next plane, under this grp's MFMAs
            if (pn < 9) {
                #pragma unroll
                for (int k = grp * 3; k < grp * 3 + 3; ++k)
                    if ((vmask >> k) & 1) pf[k] = *(const u16x8*)(srcn + goff[k]);
            }
        }
        __syncthreads();
        p = pn;
    }

    // epilogue: channel-last bf16 store + fused per-channel stats
    if (tid < 64) sred[tid] = 0.f;
    __syncthreads();

    float s[2] = {0.f, 0.f}, s2[2] = {0.f, 0.f};
    const size_t plane_out = (size_t)(a * D2 + b) * (HH * WW);
    #pragma unroll
    for (int i = 0; i < 8; ++i) {
        int h  = h0 + i;
        int w0 = wseg + kq * 4;
        #pragma unroll
        for (int nt = 0; nt < 2; ++nt) {
            int co = m + nt * 16;
            #pragma unroll
            for (int reg = 0; reg < 4; ++reg) {
                float v = acc[i][nt][reg];
                s[nt]  += v;
                s2[nt] += v * v;
                y1[(plane_out + h * WW + (w0 + reg)) * 32 + co] = f2bf(v);
            }
        }
    }
    #pragma unroll
    for (int nt = 0; nt < 2; ++nt) {
        s[nt]  += __shfl_xor(s[nt], 16);  s[nt]  += __shfl_xor(s[nt], 32);
        s2[nt] += __shfl_xor(s2[nt], 16); s2[nt] += __shfl_xor(s2[nt], 32);
    }
    if (kq == 0) {
        atomicAdd(&sred[m * 2],            s[0]);
        atomicAdd(&sred[m * 2 + 1],        s2[0]);
        atomicAdd(&sred[(m + 16) * 2],     s[1]);
        atomicAdd(&sred[(m + 16) * 2 + 1], s2[1]);
    }
    __syncthreads();
    if (tid < 64) atomicAdd(&st1[tid], sred[tid]);
}

// ---------------------------------------------------------------------------
// norm1: in-place instance-norm + leaky on y1 (channel-last bf16).
// ---------------------------------------------------------------------------
__global__ __launch_bounds__(256)
void norm1_kernel(u16* __restrict__ y1, const float* __restrict__ st1)
{
    const int tid = threadIdx.x;
    const int q   = tid & 3;
    const float invN = 1.f / (float)SPATIAL;
    float mean[8], scl[8];
    #pragma unroll
    for (int j = 0; j < 8; ++j) {
        int ci  = q * 8 + j;
        float mu = st1[ci * 2] * invN;
        float va = st1[ci * 2 + 1] * invN - mu * mu;
        mean[j] = mu;
        scl[j]  = rsqrtf(va + EPS);
    }
    #pragma unroll
    for (int j4 = 0; j4 < 4; ++j4) {
        size_t gidx = (size_t)blockIdx.x * 1024 + j4 * 256 + tid;
        u16x8* ptr = (u16x8*)(y1 + gidx * 8);
        u16x8 v = *ptr;
        u16x8 o;
        #pragma unroll
        for (int j = 0; j < 8; ++j)
            o[j] = f2bf(leaky((bf2f(v[j]) - mean[j]) * scl[j]));
        *ptr = o;
    }
}

// ---------------------------------------------------------------------------
// Conv2: Cin=32, row-shared A-frags; LDS pos stride 40 u16 (80B): 2-way free.
// B-frags load FIRST each round; prefetch spread across dw iterations.
// ---------------------------------------------------------------------------
__global__ __launch_bounds__(256, 3)
void conv2_mfma(const u16* __restrict__ y1, const u16* __restrict__ w2t,
                u16* __restrict__ y2, float* __restrict__ st2)
{
    __shared__ __align__(16) u16 lds[660 * 40];   // 52800 B
    __shared__ float sred[64];

    const int tid = threadIdx.x;
    int a, b, h0;
    decode_block(blockIdx.x, a, b, h0);
    const int lane = tid & 63;
    const int wv   = tid >> 6;
    const int kq   = lane >> 4;
    const int m    = lane & 15;
    const int wseg = wv << 4;

    unsigned pm = 0;
    #pragma unroll
    for (int p = 0; p < 9; ++p) {
        int ap = a + p / 3 - 1, bp = b + p % 3 - 1;
        if (ap >= 0 && ap < D1 && bp >= 0 && bp < D2) pm |= 1u << p;
    }

    // plane-invariant staging offsets (11 granules/thread max)
    const int p0 = tid >> 2, q = tid & 3;
    unsigned vmask = 0;
    int goff[11];
    #pragma unroll
    for (int k = 0; k < 11; ++k) {
        int pos = p0 + 64 * k;
        int row = pos / 66, col = pos - row * 66;
        int h = h0 - 1 + row, w = col - 1;
        bool v = (pos < 660) && col >= 1 && col <= 64 && h >= 0 && h < HH;
        goff[k] = v ? (h * WW + w) * 32 + q * 8 : 0;
        vmask |= (unsigned)v << k;
    }
    const int lbase = p0 * 40 + q * 8;

    for (int e = tid; e < 660; e += 256) {
        int row = e / 66, col = e - row * 66;
        int h = h0 - 1 + row;
        if (col == 0 || col == 65 || h < 0 || h >= HH) {
            u16x8 z = (u16x8)0;
            #pragma unroll
            for (int gg = 0; gg < 4; ++gg)
                *(u16x8*)&lds[e * 40 + gg * 8] = z;
        }
    }

    f32x4 acc[8][2];
    #pragma unroll
    for (int i = 0; i < 8; ++i)
        #pragma unroll
        for (int nt = 0; nt < 2; ++nt)
            acc[i][nt] = (f32x4)0.f;

    int p = 0;
    while (!((pm >> p) & 1)) ++p;

    u16x8 pf[11];
    {
        int ap = a + p / 3 - 1, bp = b + p % 3 - 1;
        const u16* src = y1 + (size_t)(ap * D2 + bp) * (HH * WW * 32);
        #pragma unroll
        for (int k = 0; k < 11; ++k)
            if ((vmask >> k) & 1) pf[k] = *(const u16x8*)(src + goff[k]);
    }

    while (p < 9) {
        int pn = p + 1;
        while (pn < 9 && !((pm >> pn) & 1)) ++pn;

        #pragma unroll
        for (int k = 0; k < 11; ++k)
            if ((vmask >> k) & 1) *(u16x8*)&lds[lbase + k * 2560] = pf[k];
        __syncthreads();

        const u16* srcn = nullptr;
        if (pn < 9)
            srcn = y1 + (size_t)((a + pn / 3 - 1) * D2 + (b + pn % 3 - 1))
                      * (HH * WW * 32);

        const u16* wbase = w2t + p * 9216;
        #pragma unroll
        for (int dw = 0; dw < 3; ++dw) {
            // B-frags first: first vmem after barrier -> MFMA waits only these
            s16x8 bf[3][2];
            #pragma unroll
            for (int dh = 0; dh < 3; ++dh) {
                const u16* wb = wbase + (dh * 3 + dw) * 1024;
                bf[dh][0] = *(const s16x8*)(wb + m * 32 + kq * 8);
                bf[dh][1] = *(const s16x8*)(wb + (m + 16) * 32 + kq * 8);
            }
            #pragma unroll
            for (int x = 0; x < 10; ++x) {
                int pos = x * 66 + wseg + dw + m;
                s16x8 af = *(const s16x8*)&lds[pos * 40 + kq * 8];
                #pragma unroll
                for (int dh = 0; dh < 3; ++dh) {
                    int i = x - dh;
                    if (i >= 0 && i < 8) {
                        acc[i][0] = __builtin_amdgcn_mfma_f32_16x16x32_bf16(af, bf[dh][0], acc[i][0], 0, 0, 0);
                        acc[i][1] = __builtin_amdgcn_mfma_f32_16x16x32_bf16(af, bf[dh][1], acc[i][1], 0, 0, 0);
                    }
                }
            }
            // progressive prefetch of next plane, under this dw's MFMAs
            if (pn < 9) {
                const int k0 = dw * 4;
                const int k1 = (dw == 2) ? 11 : (k0 + 4);
                #pragma unroll
                for (int k = k0; k < k1; ++k)
                    if ((vmask >> k) & 1) pf[k] = *(const u16x8*)(srcn + goff[k]);
            }
        }
        __syncthreads();
        p = pn;
    }

    // epilogue: channel-first bf16 + fused stats
    if (tid < 64) sred[tid] = 0.f;
    __syncthreads();

    float s[2] = {0.f, 0.f}, s2[2] = {0.f, 0.f};
    #pragma unroll
    for (int i = 0; i < 8; ++i) {
        int h  = h0 + i;
        int w0 = wseg + kq * 4;
        #pragma unroll
        for (int nt = 0; nt < 2; ++nt) {
            int co = m + nt * 16;
            u16x4 pk;
            #pragma unroll
            for (int reg = 0; reg < 4; ++reg) {
                float v = acc[i][nt][reg];
                s[nt]  += v;
                s2[nt] += v * v;
                pk[reg] = f2bf(v);
            }
            size_t off = ((size_t)(co * D1 + a) * D2 + b) * (HH * WW) + h * WW + w0;
            *(u16x4*)(y2 + off) = pk;
        }
    }
    #pragma unroll
    for (int nt = 0; nt < 2; ++nt) {
        s[nt]  += __shfl_xor(s[nt], 16);  s[nt]  += __shfl_xor(s[nt], 32);
        s2[nt] += __shfl_xor(s2[nt], 16); s2[nt] += __shfl_xor(s2[nt], 32);
    }
    if (kq == 0) {
        atomicAdd(&sred[m * 2],            s[0]);
        atomicAdd(&sred[m * 2 + 1],        s2[0]);
        atomicAdd(&sred[(m + 16) * 2],     s[1]);
        atomicAdd(&sred[(m + 16) * 2 + 1], s2[1]);
    }
    __syncthreads();
    if (tid < 64) atomicAdd(&st2[tid], sred[tid]);
}

// ---------------------------------------------------------------------------
// Final: norm + leaky, bf16 channel-first -> fp32 channel-first d_out
// ---------------------------------------------------------------------------
__global__ __launch_bounds__(256)
void norm2_kernel(const u16* __restrict__ y2, const float* __restrict__ st2,
                  float* __restrict__ out)
{
    size_t i4 = (size_t)blockIdx.x * 256 + threadIdx.x;
    int c = (int)(i4 >> 17);
    const float invN = 1.f / (float)SPATIAL;
    float mu = st2[c * 2] * invN;
    float va = st2[c * 2 + 1] * invN - mu * mu;
    float sc = rsqrtf(va + EPS);
    u16x4 v = *(const u16x4*)(y2 + i4 * 4);
    float4 o;
    o.x = leaky((bf2f(v[0]) - mu) * sc);
    o.y = leaky((bf2f(v[1]) - mu) * sc);
    o.z = leaky((bf2f(v[2]) - mu) * sc);
    o.w = leaky((bf2f(v[3]) - mu) * sc);
    *(float4*)(out + i4 * 4) = o;
}

// ---------------------------------------------------------------------------
extern "C" void kernel_launch(void* const* d_in, const int* in_sizes, int n_in,
                              void* d_out, int out_size, void* d_ws, size_t ws_size,
                              hipStream_t stream)
{
    const float* image = (const float*)d_in[0];
    const float* w1    = (const float*)d_in[1];
    const float* w2    = (const float*)d_in[2];
    float* out = (float*)d_out;

    // ws: [0,32MB) imgT (reused as y2) | [32MB,64MB) y1 | [64MB,+512B) stats
    u16*   imgT = (u16*)d_ws;
    u16*   y1   = (u16*)((char*)d_ws + 33554432);
    u16*   y2   = imgT;
    float* st   = (float*)((char*)d_ws + 67108864);
    float* st1  = st;
    float* st2  = st + 64;

    // weight tables live in d_out's tail; dead before norm2 overwrites d_out
    u16* w1t = (u16*)((char*)d_out + 66832384);   // 55296 bf16
    u16* w2t = (u16*)((char*)d_out + 66942976);   // 82944 bf16

    prep<<<2589, 256, 0, stream>>>(image, w1, w2, imgT, w1t, w2t, st);

    conv1_mfma<<<1024, 256, 0, stream>>>(imgT, w1t, y1, st1);
    norm1_kernel<<<2048, 256, 0, stream>>>(y1, st1);
    conv2_mfma<<<1024, 256, 0, stream>>>(y1, w2t, y2, st2);
    norm2_kernel<<<16384, 256, 0, stream>>>(y2, st2, out);
}